// Round 1
// baseline (545.398 us; speedup 1.0000x reference)
//
#include <hip/hip_runtime.h>
#include <stdint.h>

#define BATCHN 16384
#define NJ 21
#define DIM 128
#define NH 8
#define FFD 256
#define BB 3

typedef __attribute__((ext_vector_type(8))) short short8;
typedef __attribute__((ext_vector_type(4))) float f32x4;

__device__ __forceinline__ ushort f2bf(float f) {
  uint32_t u = __builtin_bit_cast(uint32_t, f);
  u += 0x7fffu + ((u >> 16) & 1u);
  return (ushort)(u >> 16);
}
__device__ __forceinline__ float bf2f(ushort h) {
  return __builtin_bit_cast(float, (uint32_t)h << 16);
}

// MediaPipe hand skeleton adjacency (incl. self), padded to 6 slots
__device__ const int d_nbr[21][6] = {
  {0,1,5,9,13,17},{0,1,2,0,0,0},{1,2,3,0,0,0},{2,3,4,0,0,0},{3,4,0,0,0,0},
  {0,5,6,0,0,0},{5,6,7,0,0,0},{6,7,8,0,0,0},{7,8,0,0,0,0},
  {0,9,10,0,0,0},{9,10,11,0,0,0},{10,11,12,0,0,0},{11,12,0,0,0,0},
  {0,13,14,0,0,0},{13,14,15,0,0,0},{14,15,16,0,0,0},{15,16,0,0,0,0},
  {0,17,18,0,0,0},{17,18,19,0,0,0},{18,19,20,0,0,0},{19,20,0,0,0,0}};
__device__ const int d_ncnt[21] = {6,3,3,3,2,3,3,3,2,3,3,3,2,3,3,3,2,3,3,3,2};

// Pack fp32 weights [K][N] row-major -> bf16 MFMA B-fragment layout:
// packed[((nt*(K/32)+kb)*64 + lane)*8 + j] = bf16(W[kb*32 + (lane>>4)*8 + j][nt*16 + (lane&15)])
__global__ void pack_w(const float* __restrict__ Wq, const float* __restrict__ Wk,
                       const float* __restrict__ Wv, const float* __restrict__ Wo,
                       const float* __restrict__ W1, const float* __restrict__ W2,
                       ushort* __restrict__ out) {
  int t = blockIdx.x * 256 + threadIdx.x;  // 0..131071
  const float* W;
  int base, K, N, e;
  if (t < 65536) {
    int m = t >> 14;
    W = (m == 0) ? Wq : (m == 1) ? Wk : (m == 2) ? Wv : Wo;
    base = m << 14; K = 128; N = 128; e = t & 16383;
  } else if (t < 98304) {
    W = W1; base = 65536; K = 128; N = 256; e = t - 65536;
  } else {
    W = W2; base = 98304; K = 256; N = 128; e = t - 98304;
  }
  int kbc = K / 32;
  int nt = e / (kbc * 512);
  int rem = e - nt * (kbc * 512);
  int kb = rem >> 9;
  int l = (rem & 511) >> 3;
  int j = rem & 7;
  int k = kb * 32 + ((l >> 4) << 3) + j;
  int n = nt * 16 + (l & 15);
  out[base + e] = f2bf(W[k * N + n]);
}

// One GEMM phase: D[64 x 16*ntiles] = A[64 x 32*KBLKS] @ Wpacked + bias,
// A from LDS (swizzled, row stride aRS ushorts), D -> LDS bf16 (swizzled).
// Wave w handles ntiles nt = w + 4*i.
template <int KBLKS, int NT_PER_WAVE, bool RELU>
__device__ __forceinline__ void gemm_tile(ushort* sm, int aBase, int aRS,
                                          int dBase, int dRS,
                                          const ushort* __restrict__ wp,
                                          const float* __restrict__ bias,
                                          int lane, int w) {
  short8 afr[4][KBLKS];
#pragma unroll
  for (int mt = 0; mt < 4; ++mt) {
#pragma unroll
    for (int kb = 0; kb < KBLKS; ++kb) {
      int r = mt * 16 + (lane & 15);
      int c = kb * 32 + ((lane >> 4) << 3);
      afr[mt][kb] = *(const short8*)&sm[aBase + r * aRS + (c ^ ((r & 7) << 3))];
    }
  }
#pragma unroll
  for (int i = 0; i < NT_PER_WAVE; ++i) {
    int nt = w + 4 * i;
    short8 bfr[KBLKS];
#pragma unroll
    for (int kb = 0; kb < KBLKS; ++kb)
      bfr[kb] = *(const short8*)&wp[(nt * KBLKS + kb) * 512 + lane * 8];
    int col = nt * 16 + (lane & 15);
    float bv = bias[col];
#pragma unroll
    for (int mt = 0; mt < 4; ++mt) {
      f32x4 acc = {0.f, 0.f, 0.f, 0.f};
#pragma unroll
      for (int kb = 0; kb < KBLKS; ++kb)
        acc = __builtin_amdgcn_mfma_f32_16x16x32_bf16(afr[mt][kb], bfr[kb], acc, 0, 0, 0);
#pragma unroll
      for (int i2 = 0; i2 < 4; ++i2) {
        int r = mt * 16 + ((lane >> 4) << 2) + i2;
        float v = acc[i2] + bv;
        if (RELU) v = fmaxf(v, 0.f);
        sm[dBase + r * dRS + (col ^ ((r & 7) << 3))] = f2bf(v);
      }
    }
  }
}

__global__ __launch_bounds__(256, 2)
void gat_fused(const float* __restrict__ tok, const ushort* __restrict__ wpk,
               const float* __restrict__ bq, const float* __restrict__ bk,
               const float* __restrict__ bv, const float* __restrict__ bo,
               const float* __restrict__ g1, const float* __restrict__ be1,
               const float* __restrict__ g2, const float* __restrict__ be2,
               const float* __restrict__ bf1, const float* __restrict__ bf2,
               float* __restrict__ out) {
  __shared__ ushort sm[32768];  // 64 KiB: 4 regions of 16 KiB (8192 ushorts)
  const int tid = threadIdx.x;
  const int lane = tid & 63, w = tid >> 6;
  const int gb = blockIdx.x * BB;
  const int nb = min(BB, BATCHN - gb);
  const int nrows = nb * NJ;
  const int R0 = 0, R1 = 8192, R2 = 16384, R3 = 24576;

  // ---- Phase 1a: stage tokens -> X bf16 (R0), swizzled ----
  {
    const float4* tp = (const float4*)(tok + (size_t)gb * NJ * DIM);
    for (int i = tid; i < nrows * 16; i += 256) {
      int r = i >> 4, c8 = (i & 15) << 3;
      float4 fa = tp[2 * i], fb = tp[2 * i + 1];
      uint4 u;
      u.x = f2bf(fa.x) | ((uint32_t)f2bf(fa.y) << 16);
      u.y = f2bf(fa.z) | ((uint32_t)f2bf(fa.w) << 16);
      u.z = f2bf(fb.x) | ((uint32_t)f2bf(fb.y) << 16);
      u.w = f2bf(fb.z) | ((uint32_t)f2bf(fb.w) << 16);
      *(uint4*)&sm[R0 + r * DIM + (c8 ^ ((r & 7) << 3))] = u;
    }
  }
  __syncthreads();

  // ---- Phase 1b: Q,K,V = X@W + b  (R0 -> R1,R2,R3) ----
  gemm_tile<4, 2, false>(sm, R0, DIM, R1, DIM, wpk, bq, lane, w);
  gemm_tile<4, 2, false>(sm, R0, DIM, R2, DIM, wpk + 16384, bk, lane, w);
  gemm_tile<4, 2, false>(sm, R0, DIM, R3, DIM, wpk + 32768, bv, lane, w);
  __syncthreads();

  // ---- Phase 2: sparse masked attention (VALU), ATT -> R0 ----
  for (int it = tid; it < nb * NH * NJ; it += 256) {
    int b = it / (NH * NJ);
    int rem = it - b * (NH * NJ);
    int h = rem / NJ;
    int q = rem - h * NJ;
    int r = b * NJ + q;
    int hc = h << 4;
    float qf[16], av[16];
#pragma unroll
    for (int hf = 0; hf < 2; ++hf) {
      short8 qv = *(const short8*)&sm[R1 + r * DIM + ((hc + hf * 8) ^ ((r & 7) << 3))];
#pragma unroll
      for (int j = 0; j < 8; ++j) qf[hf * 8 + j] = bf2f((ushort)qv[j]);
    }
    int cnt = d_ncnt[q];
    float sc[6];
#pragma unroll
    for (int n = 0; n < 6; ++n) {
      int rk = b * NJ + d_nbr[q][n];
      float d = 0.f;
#pragma unroll
      for (int hf = 0; hf < 2; ++hf) {
        short8 kv = *(const short8*)&sm[R2 + rk * DIM + ((hc + hf * 8) ^ ((rk & 7) << 3))];
#pragma unroll
        for (int j = 0; j < 8; ++j) d += qf[hf * 8 + j] * bf2f((ushort)kv[j]);
      }
      sc[n] = (n < cnt) ? d * 0.25f : -__builtin_inff();
    }
    float mx = sc[0];
#pragma unroll
    for (int n = 1; n < 6; ++n) mx = fmaxf(mx, sc[n]);
    float ssum = 0.f;
#pragma unroll
    for (int n = 0; n < 6; ++n) { sc[n] = __expf(sc[n] - mx); ssum += sc[n]; }
    float inv = 1.f / ssum;
#pragma unroll
    for (int j = 0; j < 16; ++j) av[j] = 0.f;
#pragma unroll
    for (int n = 0; n < 6; ++n) {
      int rk = b * NJ + d_nbr[q][n];
      float wgt = sc[n];
#pragma unroll
      for (int hf = 0; hf < 2; ++hf) {
        short8 vv = *(const short8*)&sm[R3 + rk * DIM + ((hc + hf * 8) ^ ((rk & 7) << 3))];
#pragma unroll
        for (int j = 0; j < 8; ++j) av[hf * 8 + j] += wgt * bf2f((ushort)vv[j]);
      }
    }
#pragma unroll
    for (int hf = 0; hf < 2; ++hf) {
      uint4 u;
      u.x = f2bf(av[hf * 8 + 0] * inv) | ((uint32_t)f2bf(av[hf * 8 + 1] * inv) << 16);
      u.y = f2bf(av[hf * 8 + 2] * inv) | ((uint32_t)f2bf(av[hf * 8 + 3] * inv) << 16);
      u.z = f2bf(av[hf * 8 + 4] * inv) | ((uint32_t)f2bf(av[hf * 8 + 5] * inv) << 16);
      u.w = f2bf(av[hf * 8 + 6] * inv) | ((uint32_t)f2bf(av[hf * 8 + 7] * inv) << 16);
      *(uint4*)&sm[R0 + r * DIM + ((hc + hf * 8) ^ ((r & 7) << 3))] = u;
    }
  }
  __syncthreads();

  // ---- Phase 3: P1 = ATT@Wo + bo  (R0 -> R1) ----
  gemm_tile<4, 2, false>(sm, R0, DIM, R1, DIM, wpk + 49152, bo, lane, w);
  __syncthreads();

  // ---- Phase 4: X1 = LN1(tokens + P1) -> R2 (bf16, swizzled) ----
  {
    int r = tid >> 2, qd = tid & 3;
    if (r < nrows) {
      float x[32];
      const float* trow = tok + ((size_t)(gb * NJ + r)) * DIM + qd * 32;
#pragma unroll
      for (int i = 0; i < 4; ++i) {
        int c = qd * 32 + i * 8;
        short8 pv = *(const short8*)&sm[R1 + r * DIM + (c ^ ((r & 7) << 3))];
        float4 t0 = *(const float4*)(trow + i * 8);
        float4 t1 = *(const float4*)(trow + i * 8 + 4);
        x[i * 8 + 0] = bf2f((ushort)pv[0]) + t0.x;
        x[i * 8 + 1] = bf2f((ushort)pv[1]) + t0.y;
        x[i * 8 + 2] = bf2f((ushort)pv[2]) + t0.z;
        x[i * 8 + 3] = bf2f((ushort)pv[3]) + t0.w;
        x[i * 8 + 4] = bf2f((ushort)pv[4]) + t1.x;
        x[i * 8 + 5] = bf2f((ushort)pv[5]) + t1.y;
        x[i * 8 + 6] = bf2f((ushort)pv[6]) + t1.z;
        x[i * 8 + 7] = bf2f((ushort)pv[7]) + t1.w;
      }
      float s = 0.f, s2 = 0.f;
#pragma unroll
      for (int j = 0; j < 32; ++j) { s += x[j]; s2 += x[j] * x[j]; }
      s += __shfl_xor(s, 1); s += __shfl_xor(s, 2);
      s2 += __shfl_xor(s2, 1); s2 += __shfl_xor(s2, 2);
      float mu = s * 0.0078125f;
      float var = s2 * 0.0078125f - mu * mu;
      float rstd = rsqrtf(var + 1e-5f);
#pragma unroll
      for (int i = 0; i < 4; ++i) {
        int c = qd * 32 + i * 8;
        float4 ga = *(const float4*)(g1 + c), gc = *(const float4*)(g1 + c + 4);
        float4 ba = *(const float4*)(be1 + c), bc = *(const float4*)(be1 + c + 4);
        float y0 = (x[i * 8 + 0] - mu) * rstd * ga.x + ba.x;
        float y1 = (x[i * 8 + 1] - mu) * rstd * ga.y + ba.y;
        float y2 = (x[i * 8 + 2] - mu) * rstd * ga.z + ba.z;
        float y3 = (x[i * 8 + 3] - mu) * rstd * ga.w + ba.w;
        float y4 = (x[i * 8 + 4] - mu) * rstd * gc.x + bc.x;
        float y5 = (x[i * 8 + 5] - mu) * rstd * gc.y + bc.y;
        float y6 = (x[i * 8 + 6] - mu) * rstd * gc.z + bc.z;
        float y7 = (x[i * 8 + 7] - mu) * rstd * gc.w + bc.w;
        uint4 u;
        u.x = f2bf(y0) | ((uint32_t)f2bf(y1) << 16);
        u.y = f2bf(y2) | ((uint32_t)f2bf(y3) << 16);
        u.z = f2bf(y4) | ((uint32_t)f2bf(y5) << 16);
        u.w = f2bf(y6) | ((uint32_t)f2bf(y7) << 16);
        *(uint4*)&sm[R2 + r * DIM + (c ^ ((r & 7) << 3))] = u;
      }
    }
  }
  __syncthreads();

  // ---- Phase 5: H = relu(X1@W1 + bf1) -> R0..R1 as [64][256] ----
  gemm_tile<4, 4, true>(sm, R2, DIM, 0, FFD, wpk + 65536, bf1, lane, w);
  __syncthreads();

  // ---- Phase 6: P2 = H@W2 + bf2 -> R3 ----
  gemm_tile<8, 2, false>(sm, 0, FFD, R3, DIM, wpk + 98304, bf2, lane, w);
  __syncthreads();

  // ---- Phase 7: out = LN2(X1 + P2) -> global fp32 ----
  {
    int r = tid >> 2, qd = tid & 3;
    if (r < nrows) {
      float x[32];
#pragma unroll
      for (int i = 0; i < 4; ++i) {
        int c = qd * 32 + i * 8;
        short8 pv = *(const short8*)&sm[R3 + r * DIM + (c ^ ((r & 7) << 3))];
        short8 xv = *(const short8*)&sm[R2 + r * DIM + (c ^ ((r & 7) << 3))];
#pragma unroll
        for (int j = 0; j < 8; ++j)
          x[i * 8 + j] = bf2f((ushort)pv[j]) + bf2f((ushort)xv[j]);
      }
      float s = 0.f, s2 = 0.f;
#pragma unroll
      for (int j = 0; j < 32; ++j) { s += x[j]; s2 += x[j] * x[j]; }
      s += __shfl_xor(s, 1); s += __shfl_xor(s, 2);
      s2 += __shfl_xor(s2, 1); s2 += __shfl_xor(s2, 2);
      float mu = s * 0.0078125f;
      float var = s2 * 0.0078125f - mu * mu;
      float rstd = rsqrtf(var + 1e-5f);
      float* orow = out + ((size_t)(gb * NJ + r)) * DIM + qd * 32;
#pragma unroll
      for (int i = 0; i < 4; ++i) {
        int c = qd * 32 + i * 8;
        float4 ga = *(const float4*)(g2 + c), gc = *(const float4*)(g2 + c + 4);
        float4 ba = *(const float4*)(be2 + c), bc = *(const float4*)(be2 + c + 4);
        float4 o0, o1;
        o0.x = (x[i * 8 + 0] - mu) * rstd * ga.x + ba.x;
        o0.y = (x[i * 8 + 1] - mu) * rstd * ga.y + ba.y;
        o0.z = (x[i * 8 + 2] - mu) * rstd * ga.z + ba.z;
        o0.w = (x[i * 8 + 3] - mu) * rstd * ga.w + ba.w;
        o1.x = (x[i * 8 + 4] - mu) * rstd * gc.x + bc.x;
        o1.y = (x[i * 8 + 5] - mu) * rstd * gc.y + bc.y;
        o1.z = (x[i * 8 + 6] - mu) * rstd * gc.z + bc.z;
        o1.w = (x[i * 8 + 7] - mu) * rstd * gc.w + bc.w;
        *(float4*)(orow + i * 8) = o0;
        *(float4*)(orow + i * 8 + 4) = o1;
      }
    }
  }
}

extern "C" void kernel_launch(void* const* d_in, const int* in_sizes, int n_in,
                              void* d_out, int out_size, void* d_ws, size_t ws_size,
                              hipStream_t stream) {
  const float* tok = (const float*)d_in[0];
  const float* Wq = (const float*)d_in[1];
  const float* bq = (const float*)d_in[2];
  const float* Wk = (const float*)d_in[3];
  const float* bk = (const float*)d_in[4];
  const float* Wv = (const float*)d_in[5];
  const float* bv = (const float*)d_in[6];
  const float* Wo = (const float*)d_in[7];
  const float* bo = (const float*)d_in[8];
  const float* g1 = (const float*)d_in[9];
  const float* be1 = (const float*)d_in[10];
  const float* g2 = (const float*)d_in[11];
  const float* be2 = (const float*)d_in[12];
  const float* W1 = (const float*)d_in[13];
  const float* bf1 = (const float*)d_in[14];
  const float* W2 = (const float*)d_in[15];
  const float* bf2 = (const float*)d_in[16];
  ushort* wpk = (ushort*)d_ws;  // 262144 bytes used

  pack_w<<<dim3(512), dim3(256), 0, stream>>>(Wq, Wk, Wv, Wo, W1, W2, wpk);
  int nblk = (BATCHN + BB - 1) / BB;
  gat_fused<<<dim3(nblk), dim3(256), 0, stream>>>(
      tok, wpk, bq, bk, bv, bo, g1, be1, g2, be2, bf1, bf2, (float*)d_out);
}